// Round 1
// baseline (205.775 us; speedup 1.0000x reference)
//
#include <hip/hip_runtime.h>

#define TT 4096          // signal length
#define NN 8192          // padded length (2*TT)
#define NF 4096          // half-length FFT size (8^4)
#define LDSN 4224        // 4096 + bank-conflict padding (PHYS(4095)=4222)

#define PHYS(i) ((i) + ((i) >> 5))

__device__ __forceinline__ int digitrev12(int k) {
    // radix-8 digit reversal of a 12-bit index
    return ((k & 7) << 9) | (((k >> 3) & 7) << 6) | (((k >> 6) & 7) << 3) | ((k >> 9) & 7);
}

__device__ __forceinline__ void cmul(float ar, float ai, float br, float bi,
                                     float& cr, float& ci) {
    cr = ar * br - ai * bi;
    ci = ar * bi + ai * br;
}

// In-place radix-8 DIF FFT of 4096 points held in LDS (SoA, padded).
// S=-1: forward (e^{-2pi i}), S=+1: inverse/unnormalized (e^{+2pi i}).
// Output is digit-reversed: X[k] ends up at PHYS(digitrev12(k)).
// tw[m] = e^{-2*pi*i*m/8192} (double-precision-accurate table).
template<int S>
__device__ void fft4096(float* lre, float* lim, int tid, const float2* __restrict__ tw) {
    #pragma unroll
    for (int stage = 0; stage < 4; ++stage) {
        const int lm = 9 - 3 * stage;        // log2(M), M = butterfly stride
        const int M = 1 << lm;
        const int twsh = 10 - lm;            // tw index = j * (8192/L), L = 8*M
        __syncthreads();
        #pragma unroll
        for (int it = 0; it < 2; ++it) {
            const int beta = tid + 256 * it;         // butterfly id, 512/stage
            const int j = beta & (M - 1);
            const int b0 = (beta >> lm) << (lm + 3);
            const int base = b0 + j;

            float xr[8], xi[8];
            #pragma unroll
            for (int q = 0; q < 8; ++q) {
                const int ph = PHYS(base + (q << lm));
                xr[q] = lre[ph];
                xi[q] = lim[ph];
            }

            // DFT8 = two DFT4s + combine.  S*i*(a+bi) = (-S*b, S*a)
            float t0r = xr[0] + xr[4], t0i = xi[0] + xi[4];
            float t1r = xr[0] - xr[4], t1i = xi[0] - xi[4];
            float t2r = xr[2] + xr[6], t2i = xi[2] + xi[6];
            float t3r = xr[2] - xr[6], t3i = xi[2] - xi[6];
            float e0r = t0r + t2r, e0i = t0i + t2i;
            float e2r = t0r - t2r, e2i = t0i - t2i;
            float e1r = t1r - S * t3i, e1i = t1i + S * t3r;
            float e3r = t1r + S * t3i, e3i = t1i - S * t3r;

            float u0r = xr[1] + xr[5], u0i = xi[1] + xi[5];
            float u1r = xr[1] - xr[5], u1i = xi[1] - xi[5];
            float u2r = xr[3] + xr[7], u2i = xi[3] + xi[7];
            float u3r = xr[3] - xr[7], u3i = xi[3] - xi[7];
            float o0r = u0r + u2r, o0i = u0i + u2i;
            float o2r = u0r - u2r, o2i = u0i - u2i;
            float o1r = u1r - S * u3i, o1i = u1i + S * u3r;
            float o3r = u1r + S * u3i, o3i = u1i - S * u3r;

            const float C = 0.70710678118654752f;
            float w1or = C * (o1r - S * o1i), w1oi = C * (o1i + S * o1r);
            float w2or = -S * o2i,            w2oi = S * o2r;
            float w3or = -C * (o3r + S * o3i), w3oi = C * (S * o3r - o3i);

            float y0r = e0r + o0r,  y0i = e0i + o0i;
            float y4r = e0r - o0r,  y4i = e0i - o0i;
            float y1r = e1r + w1or, y1i = e1i + w1oi;
            float y5r = e1r - w1or, y5i = e1i - w1oi;
            float y2r = e2r + w2or, y2i = e2i + w2oi;
            float y6r = e2r - w2or, y6i = e2i - w2oi;
            float y3r = e3r + w3or, y3i = e3i + w3oi;
            float y7r = e3r - w3or, y7i = e3i - w3oi;

            // Twiddle W = e^{S*2pi*i*j/L}; powers via mul chain (error < few ulp)
            const float2 t = tw[j << twsh];
            const float w1r = t.x;
            const float w1i = (S > 0) ? -t.y : t.y;
            float w2r, w2i, w3r, w3i, w4r, w4i, w5r, w5i, w6r, w6i, w7r, w7i;
            cmul(w1r, w1i, w1r, w1i, w2r, w2i);
            cmul(w2r, w2i, w1r, w1i, w3r, w3i);
            cmul(w2r, w2i, w2r, w2i, w4r, w4i);
            cmul(w4r, w4i, w1r, w1i, w5r, w5i);
            cmul(w3r, w3i, w3r, w3i, w6r, w6i);
            cmul(w4r, w4i, w3r, w3i, w7r, w7i);

            int ph = PHYS(base);
            lre[ph] = y0r; lim[ph] = y0i;
            float rr, ri;
            ph = PHYS(base + (1 << lm)); cmul(y1r, y1i, w1r, w1i, rr, ri); lre[ph] = rr; lim[ph] = ri;
            ph = PHYS(base + (2 << lm)); cmul(y2r, y2i, w2r, w2i, rr, ri); lre[ph] = rr; lim[ph] = ri;
            ph = PHYS(base + (3 << lm)); cmul(y3r, y3i, w3r, w3i, rr, ri); lre[ph] = rr; lim[ph] = ri;
            ph = PHYS(base + (4 << lm)); cmul(y4r, y4i, w4r, w4i, rr, ri); lre[ph] = rr; lim[ph] = ri;
            ph = PHYS(base + (5 << lm)); cmul(y5r, y5i, w5r, w5i, rr, ri); lre[ph] = rr; lim[ph] = ri;
            ph = PHYS(base + (6 << lm)); cmul(y6r, y6i, w6r, w6i, rr, ri); lre[ph] = rr; lim[ph] = ri;
            ph = PHYS(base + (7 << lm)); cmul(y7r, y7i, w7r, w7i, rr, ri); lre[ph] = rr; lim[ph] = ri;
        }
    }
}

// twiddle table: tw[k] = e^{-2*pi*i*k/8192}, computed in double once per launch
__global__ __launch_bounds__(256) void tw_init(float2* tw) {
    int k = blockIdx.x * 256 + threadIdx.x;
    double a = (-2.0 * 3.14159265358979323846 / (double)NN) * (double)k;
    tw[k] = make_float2((float)cos(a), (float)sin(a));
}

__device__ __forceinline__ int refl(int p) {
    // reflection-padded index into the original T=4096 row, p in [0, 8192)
    if (p < 2048) return 2047 - p;
    if (p < 6144) return p - 2048;
    return 10239 - p;
}

// Forward: real 8192-FFT per batch row via packed complex-4096 FFT + untangle.
// Writes F[b][i] = X[i+1] for i in [0,4096)  (bins 1..4096 are all we need).
__global__ __launch_bounds__(256) void fwd_kernel(const float* __restrict__ in,
                                                  float2* __restrict__ F,
                                                  const float2* __restrict__ tw) {
    __shared__ float lre[LDSN], lim[LDSN];
    const int b = blockIdx.x, tid = threadIdx.x;
    const float* row = in + b * TT;

    for (int i = tid; i < NF; i += 256) {
        lre[PHYS(i)] = row[refl(2 * i)];
        lim[PHYS(i)] = row[refl(2 * i + 1)];
    }

    fft4096<-1>(lre, lim, tid, tw);
    __syncthreads();

    for (int i = tid; i < NF; i += 256) {
        const int k = i + 1;
        const int pa = PHYS(digitrev12(k & (NF - 1)));
        const int pb = PHYS(digitrev12((NF - k) & (NF - 1)));
        const float zr = lre[pa], zi = lim[pa];
        const float wr = lre[pb], wi = lim[pb];
        // Fe = (z + conj(w))/2 ; Fo = -i(z - conj(w))/2
        const float fer = 0.5f * (zr + wr), fei = 0.5f * (zi - wi);
        const float for_ = 0.5f * (zi + wi), foi = -0.5f * (zr - wr);
        const float2 t = tw[k];           // e^{-2pi i k/8192}
        const float xr = fer + t.x * for_ - t.y * foi;
        const float xi = fei + t.x * foi + t.y * for_;
        F[b * NF + i] = make_float2(xr, xi);
    }
}

// Inverse: one block per (b, scale).  d_k = F[b,k]*wft[j,k+1], k in [0,4096).
// |z[t]| is invariant under the one-bin spectral shift, and with support in
// the lower half-band the length-8192 IFFT splits into two length-4096 IFFTs
// (even samples: IFFT(d); odd samples: IFFT(d * e^{+2pi i k/8192})).
__global__ __launch_bounds__(256) void inv_kernel(const float2* __restrict__ F,
                                                  const float* __restrict__ wft,
                                                  float* __restrict__ out,
                                                  const float2* __restrict__ tw,
                                                  int NS) {
    __shared__ float lre[LDSN], lim[LDSN];
    const int blk = blockIdx.x;
    const int b = blk / NS;
    const int j = blk - b * NS;
    const int tid = threadIdx.x;

    const float2* Frow = F + b * NF;
    const float* wrow = wft + (size_t)j * NN + 1;   // bins 1..4096

    float dre[16], dim[16];
    #pragma unroll
    for (int r = 0; r < 16; ++r) {
        const int k = tid + 256 * r;
        const float2 f = Frow[k];
        const float w = wrow[k];
        dre[r] = f.x * w;
        dim[r] = f.y * w;
    }

    float v0[8];
    float* orow = out + (size_t)(b * NS + j) * TT;
    const float LOGN = 9.0109131020007136f;   // log(8192)

    #pragma unroll
    for (int pass = 0; pass < 2; ++pass) {
        __syncthreads();   // protect LDS reuse vs previous pass reads
        if (pass == 0) {
            #pragma unroll
            for (int r = 0; r < 16; ++r) {
                const int k = tid + 256 * r;
                lre[PHYS(k)] = dre[r];
                lim[PHYS(k)] = dim[r];
            }
        } else {
            #pragma unroll
            for (int r = 0; r < 16; ++r) {
                const int k = tid + 256 * r;
                const float2 t = tw[k];        // conj -> e^{+2pi i k/8192}
                const float mr = t.x, mi = -t.y;
                lre[PHYS(k)] = dre[r] * mr - dim[r] * mi;
                lim[PHYS(k)] = dre[r] * mi + dim[r] * mr;
            }
        }

        fft4096<1>(lre, lim, tid, tw);
        __syncthreads();

        // need t' in [1024, 3072): t_global = 2t'+pass in [2048, 6144)
        #pragma unroll
        for (int i2 = 0; i2 < 8; ++i2) {
            const int tp = 1024 + tid + 256 * i2;
            const int src = PHYS(digitrev12(tp));
            const float re = lre[src], im = lim[src];
            const float val = 0.5f * logf(re * re + im * im) - LOGN;
            if (pass == 0) {
                v0[i2] = val;
            } else {
                // even/odd pair -> coalesced float2 store
                ((float2*)orow)[tid + 256 * i2] = make_float2(v0[i2], val);
            }
        }
    }
}

extern "C" void kernel_launch(void* const* d_in, const int* in_sizes, int n_in,
                              void* d_out, int out_size, void* d_ws, size_t ws_size,
                              hipStream_t stream) {
    const float* inputs = (const float*)d_in[0];
    const float* wft = (const float*)d_in[1];
    float* out = (float*)d_out;

    const int B = in_sizes[0] / TT;     // 64
    const int NS = in_sizes[1] / NN;    // 75

    float2* F = (float2*)d_ws;                                   // B*4096 cplx = 2 MB
    float2* tw = (float2*)((char*)d_ws + (size_t)B * NF * sizeof(float2)); // 64 KB

    hipLaunchKernelGGL(tw_init, dim3(NN / 256), dim3(256), 0, stream, tw);
    hipLaunchKernelGGL(fwd_kernel, dim3(B), dim3(256), 0, stream, inputs, F, tw);
    hipLaunchKernelGGL(inv_kernel, dim3(B * NS), dim3(256), 0, stream, F, wft, out, tw, NS);
}